// Round 10
// baseline (500.312 us; speedup 1.0000x reference)
//
#include <hip/hip_runtime.h>
#include <math.h>

#define NN 5000
#define NE 160000
#define NF 16
#define KS 640      // k per split (8 splits: 7x640 + 520)
#define WTS 648     // LDS k-stride (bf16): 324 words, %32=4 -> 2-way alias = free
#define CAP 128     // per-node edge bucket capacity (max in-deg ~65 @ lambda=32)
#define SCB 625     // scatter-role blocks (625*256 = 160000 = NE exact)
#define GMB 632     // gemm-role blocks (79 x-tiles * 8 k-splits)

typedef __attribute__((ext_vector_type(8))) short bf16x8;  // 4 VGPRs
typedef __attribute__((ext_vector_type(4))) float f32x4;   // MFMA acc

// ws layout (bytes):
// [0,       20000)   cur   : per-node cursor -> in-degree after scatter (zeroed)
// [20000,   340000)  h1    : x@W1 (split-k atomics -> zeroed)
// [340000,  2900000) slots : bucketed edge sources, slots[d*CAP+pos]=src
// [2900000, 3220000) a1    : relu(agg1(h1)+b1)

__device__ __forceinline__ short f2bf(float f) {  // RNE f32->bf16
  union { float f; unsigned u; } v; v.f = f;
  unsigned r = v.u + 0x7FFFu + ((v.u >> 16) & 1u);
  return (short)(r >> 16);
}

// Merged kernel: blocks [0,SCB) bucket edges by dst; blocks [SCB, SCB+GMB)
// compute h1 = x @ W1 via mfma_f32_16x16x32_bf16 (fp32 acc), split-k x8.
__global__ __launch_bounds__(256) void k_gemm_scat(const float* __restrict__ x,
                                                   const float* __restrict__ w1,
                                                   float* __restrict__ h1,
                                                   const int* __restrict__ src,
                                                   const int* __restrict__ dst,
                                                   int* __restrict__ cur,
                                                   int* __restrict__ slots) {
  __shared__ short wt[NF * WTS];  // 20736 B (unused by scatter role)
  const int bid = blockIdx.x;
  const int tid = threadIdx.x;

  if (bid < SCB) {                // ---- scatter role ----
    const int e = bid * 256 + tid;
    if (e < NE) {
      const int d = dst[e];
      const int pos = atomicAdd(&cur[d], 1);
      if (pos < CAP) slots[d * CAP + pos] = src[e];
    }
    return;                       // uniform per block; no barrier crossed
  }

  // ---- gemm role ----
  const int gb = bid - SCB;       // 0..631
  const int bx = gb % 79;
  const int by = gb / 79;
  const int lane = tid & 63;
  const int wv = tid >> 6;
  const int kb = by * KS;
  const int klen = (NN - kb < KS) ? (NN - kb) : KS;   // 640 or 520
  const int nsteps = (klen + 31) >> 5;                // 20 or 17

  // Stage W1[kb..kb+KS) -> wt[n][kk] transposed bf16, zero-padded past NN.
  for (int kk = tid; kk < KS; kk += 256) {
    const int kg = kb + kk;
    if (kg < NN) {
      const float4* __restrict__ wr = (const float4*)(w1 + (size_t)kg * NF);
      const float4 a = wr[0], b = wr[1], c = wr[2], d = wr[3];
      wt[0 * WTS + kk] = f2bf(a.x);  wt[1 * WTS + kk] = f2bf(a.y);
      wt[2 * WTS + kk] = f2bf(a.z);  wt[3 * WTS + kk] = f2bf(a.w);
      wt[4 * WTS + kk] = f2bf(b.x);  wt[5 * WTS + kk] = f2bf(b.y);
      wt[6 * WTS + kk] = f2bf(b.z);  wt[7 * WTS + kk] = f2bf(b.w);
      wt[8 * WTS + kk] = f2bf(c.x);  wt[9 * WTS + kk] = f2bf(c.y);
      wt[10 * WTS + kk] = f2bf(c.z); wt[11 * WTS + kk] = f2bf(c.w);
      wt[12 * WTS + kk] = f2bf(d.x); wt[13 * WTS + kk] = f2bf(d.y);
      wt[14 * WTS + kk] = f2bf(d.z); wt[15 * WTS + kk] = f2bf(d.w);
    } else {
#pragma unroll
      for (int n = 0; n < NF; ++n) wt[n * WTS + kk] = 0;
    }
  }
  __syncthreads();

  const int tile = bx * 4 + wv;   // 0..315 (313 real)
  const int m0 = tile * 16;
  int arow = m0 + (lane & 15);
  if (arow > NN - 1) arow = NN - 1;       // clamp addr; write guarded below
  const float* __restrict__ xr = x + (size_t)arow * NN + kb;
  const int quad = lane >> 4;
  const short* __restrict__ bp = &wt[(lane & 15) * WTS + quad * 8];

  f32x4 acc = {0.f, 0.f, 0.f, 0.f};
  for (int s = 0; s < nsteps; ++s) {
    const int k0 = s * 32 + quad * 8;     // offset within split (8-aligned)
    bf16x8 a;
    if (kb + k0 < NN) {                   // whole 8-chunk valid (NN%8==0)
      const float4 xa = *(const float4*)(xr + k0);
      const float4 xb = *(const float4*)(xr + k0 + 4);
      a[0] = f2bf(xa.x); a[1] = f2bf(xa.y); a[2] = f2bf(xa.z); a[3] = f2bf(xa.w);
      a[4] = f2bf(xb.x); a[5] = f2bf(xb.y); a[6] = f2bf(xb.z); a[7] = f2bf(xb.w);
    } else {
#pragma unroll
      for (int j = 0; j < 8; ++j) a[j] = 0;
    }
    const bf16x8 b = *(const bf16x8*)(bp + s * 32);  // ds_read_b128
    acc = __builtin_amdgcn_mfma_f32_16x16x32_bf16(a, b, acc, 0, 0, 0);
  }

  const int col = lane & 15;
#pragma unroll
  for (int r = 0; r < 4; ++r) {
    const int orow = m0 + quad * 4 + r;
    if (orow < NN) atomicAdd(&h1[orow * NF + col], acc[r]);
  }
}

// Layer-1 aggregation (gather, no atomics), fused bias+ReLU:
//   a1[v][j] = relu(inv[v]*sum_s inv[s]*h1[s][j] + inv[v]^2*h1[v][j] + b1[j])
__global__ __launch_bounds__(256) void k_gather1(const int* __restrict__ slots,
                                                 const int* __restrict__ cnt,
                                                 const float* __restrict__ bias,
                                                 const float* __restrict__ hin,
                                                 float* __restrict__ outp) {
  const int tid = threadIdx.x;
  const int lane = tid & 63;
  const int wv = tid >> 6;
  const int v = blockIdx.x * 4 + wv;
  if (v >= NN) return;
  const int j = lane & 15;
  const int eg = lane >> 4;                 // edge subgroup 0..3
  int deg = cnt[v];
  if (deg > CAP) deg = CAP;
  const int* __restrict__ sl = slots + v * CAP;

  float acc = 0.f;
  int base = 0;
  for (; base + 8 <= deg; base += 8) {      // 2 independent chains per iter
    const int s0 = sl[base + eg];
    const int s1 = sl[base + 4 + eg];
    const float iv0 = rsqrtf((float)cnt[s0] + 1.0f);
    const float iv1 = rsqrtf((float)cnt[s1] + 1.0f);
    acc += iv0 * hin[s0 * NF + j];
    acc += iv1 * hin[s1 * NF + j];
  }
  for (; base < deg; base += 4) {
    const int idx = base + eg;
    if (idx < deg) {
      const int s = sl[idx];
      acc += rsqrtf((float)cnt[s] + 1.0f) * hin[s * NF + j];
    }
  }
  acc += __shfl_xor(acc, 16);
  acc += __shfl_xor(acc, 32);

  if (lane < 16) {
    const float ivv = rsqrtf((float)deg + 1.0f);
    float r = ivv * acc + ivv * ivv * hin[v * NF + j];
    outp[v * NF + j] = fmaxf(r + bias[j], 0.f);
  }
}

// Fused layer-2 aggregation + final GEMM + log_softmax. 4 rows per block,
// 1024 threads. Phase 1: gather g2 rows from a1 (16 subgroups/node, 4 waves).
// Phase 2: z kept ENTIRELY in registers (4 rows x 8 cols/thread, static
// indices only); w2/b2/out as float4 (1KB/wave/instr); zs LDS deleted ->
// LDS ~1.6KB, no 3x80KB LDS passes, no LDS occupancy cap.
__global__ __launch_bounds__(1024) void k_final4(const int* __restrict__ slots,
                                                 const int* __restrict__ cnt,
                                                 const float* __restrict__ a1,
                                                 const float* __restrict__ w2,
                                                 const float* __restrict__ b2,
                                                 float* __restrict__ out) {
  __shared__ float pp[16][NF];      // 1024 B  per-wave gather partials
  __shared__ float gsh[4 * NF];     // 256 B
  __shared__ float red[16 * 4];     // 256 B
  __shared__ float rowmax[4];       // 16 B
  __shared__ float rowoff[4];       // 16 B
  const int tid = threadIdx.x;
  const int lane = tid & 63;
  const int wv = tid >> 6;          // 0..15
  const int row0 = blockIdx.x * 4;

  // ---- phase 1: g2 for nodes v0..v0+3 (wave wv -> node wv>>2, quarter wv&3)
  {
    const int r = wv >> 2;
    const int v = row0 + r;
    const int j = lane & 15;
    const int sg = ((wv & 3) << 2) | (lane >> 4);   // 0..15, stride 16
    int deg = cnt[v];
    if (deg > CAP) deg = CAP;
    const int* __restrict__ sl = slots + v * CAP;
    float acc = 0.f;
    for (int idx = sg; idx < deg; idx += 16) {
      const int s = sl[idx];
      acc += rsqrtf((float)cnt[s] + 1.0f) * a1[s * NF + j];
    }
    acc += __shfl_xor(acc, 16);
    acc += __shfl_xor(acc, 32);
    if (lane < 16) pp[wv][j] = acc;
  }
  __syncthreads();
  if (tid < 64) {
    const int r = tid >> 4, j = tid & 15;
    const int v = row0 + r;
    int deg = cnt[v];
    if (deg > CAP) deg = CAP;
    const float ivv = rsqrtf((float)deg + 1.0f);
    const float acc = pp[r * 4 + 0][j] + pp[r * 4 + 1][j] +
                      pp[r * 4 + 2][j] + pp[r * 4 + 3][j];
    gsh[r * NF + j] = ivv * acc + ivv * ivv * a1[v * NF + j];
  }
  __syncthreads();

  // ---- phase 2: z = g2 @ W2 + b2, all-register z, float4 memory ----
  float g[4][NF];
#pragma unroll
  for (int r = 0; r < 4; ++r)
#pragma unroll
    for (int k = 0; k < NF; ++k) g[r][k] = gsh[r * NF + k];

  const int c0 = tid * 4;               // 0..4092 (always fully valid)
  const int c1 = 4096 + tid * 4;        // 4096..8188
  const bool act1 = (c1 < NN);          // tid < 226; c1%4==0 & NN%4==0 -> whole float4 valid

  float z0[4][4], z1[4][4];
  {
    const float4 bb = *(const float4*)(b2 + c0);
#pragma unroll
    for (int r = 0; r < 4; ++r) {
      z0[r][0] = bb.x; z0[r][1] = bb.y; z0[r][2] = bb.z; z0[r][3] = bb.w;
    }
#pragma unroll
    for (int k = 0; k < NF; ++k) {
      const float4 w = *(const float4*)(w2 + (size_t)k * NN + c0);
#pragma unroll
      for (int r = 0; r < 4; ++r) {
        z0[r][0] = fmaf(g[r][k], w.x, z0[r][0]);
        z0[r][1] = fmaf(g[r][k], w.y, z0[r][1]);
        z0[r][2] = fmaf(g[r][k], w.z, z0[r][2]);
        z0[r][3] = fmaf(g[r][k], w.w, z0[r][3]);
      }
    }
  }
  if (act1) {
    const float4 bb = *(const float4*)(b2 + c1);
#pragma unroll
    for (int r = 0; r < 4; ++r) {
      z1[r][0] = bb.x; z1[r][1] = bb.y; z1[r][2] = bb.z; z1[r][3] = bb.w;
    }
#pragma unroll
    for (int k = 0; k < NF; ++k) {
      const float4 w = *(const float4*)(w2 + (size_t)k * NN + c1);
#pragma unroll
      for (int r = 0; r < 4; ++r) {
        z1[r][0] = fmaf(g[r][k], w.x, z1[r][0]);
        z1[r][1] = fmaf(g[r][k], w.y, z1[r][1]);
        z1[r][2] = fmaf(g[r][k], w.z, z1[r][2]);
        z1[r][3] = fmaf(g[r][k], w.w, z1[r][3]);
      }
    }
  }

  // block-wide row max
  float mx[4];
#pragma unroll
  for (int r = 0; r < 4; ++r) {
    float m = fmaxf(fmaxf(z0[r][0], z0[r][1]), fmaxf(z0[r][2], z0[r][3]));
    if (act1)
      m = fmaxf(m, fmaxf(fmaxf(z1[r][0], z1[r][1]), fmaxf(z1[r][2], z1[r][3])));
    for (int off = 32; off; off >>= 1) m = fmaxf(m, __shfl_xor(m, off));
    mx[r] = m;
  }
  if (lane == 0) {
#pragma unroll
    for (int r = 0; r < 4; ++r) red[wv * 4 + r] = mx[r];
  }
  __syncthreads();
  if (tid < 4) {
    float m = red[tid];
#pragma unroll
    for (int w = 1; w < 16; ++w) m = fmaxf(m, red[w * 4 + tid]);
    rowmax[tid] = m;
  }
  __syncthreads();
  const float rm0 = rowmax[0], rm1 = rowmax[1], rm2 = rowmax[2], rm3 = rowmax[3];

  // block-wide row sum of exp(z - rowmax), z from registers
  float sm[4];
  {
    const float rms[4] = {rm0, rm1, rm2, rm3};
#pragma unroll
    for (int r = 0; r < 4; ++r) {
      float s = __expf(z0[r][0] - rms[r]) + __expf(z0[r][1] - rms[r]) +
                __expf(z0[r][2] - rms[r]) + __expf(z0[r][3] - rms[r]);
      if (act1)
        s += __expf(z1[r][0] - rms[r]) + __expf(z1[r][1] - rms[r]) +
             __expf(z1[r][2] - rms[r]) + __expf(z1[r][3] - rms[r]);
      for (int off = 32; off; off >>= 1) s += __shfl_xor(s, off);
      sm[r] = s;
    }
  }
  if (lane == 0) {
#pragma unroll
    for (int r = 0; r < 4; ++r) red[wv * 4 + r] = sm[r];
  }
  __syncthreads();
  if (tid < 4) {
    float s = red[tid];
#pragma unroll
    for (int w = 1; w < 16; ++w) s += red[w * 4 + tid];
    rowoff[tid] = rowmax[tid] + logf(s);
  }
  __syncthreads();

  // write out = z - rowoff, float4 stores from registers
  {
    const float o[4] = {rowoff[0], rowoff[1], rowoff[2], rowoff[3]};
#pragma unroll
    for (int r = 0; r < 4; ++r) {
      float4 v;
      v.x = z0[r][0] - o[r]; v.y = z0[r][1] - o[r];
      v.z = z0[r][2] - o[r]; v.w = z0[r][3] - o[r];
      *(float4*)(out + (size_t)(row0 + r) * NN + c0) = v;
    }
    if (act1) {
#pragma unroll
      for (int r = 0; r < 4; ++r) {
        float4 v;
        v.x = z1[r][0] - o[r]; v.y = z1[r][1] - o[r];
        v.z = z1[r][2] - o[r]; v.w = z1[r][3] - o[r];
        *(float4*)(out + (size_t)(row0 + r) * NN + c1) = v;
      }
    }
  }
}

extern "C" void kernel_launch(void* const* d_in, const int* in_sizes, int n_in,
                              void* d_out, int out_size, void* d_ws, size_t ws_size,
                              hipStream_t stream) {
  const float* x  = (const float*)d_in[0];
  const int*   src = (const int*)d_in[1];
  const int*   dst = (const int*)d_in[2];
  const float* W1 = (const float*)d_in[3];
  const float* b1 = (const float*)d_in[4];
  const float* W2 = (const float*)d_in[5];
  const float* b2 = (const float*)d_in[6];
  float* out = (float*)d_out;

  char* ws = (char*)d_ws;
  int*   cur   = (int*)(ws);                // [0, 20000)
  float* h1    = (float*)(ws + 20000);      // [20000, 340000)
  int*   slots = (int*)(ws + 340000);       // [340000, 2900000)
  float* a1    = (float*)(ws + 2900000);    // [2900000, 3220000)

  // zero cur + h1 (scatter cursors; split-k atomics accumulate into h1)
  hipMemsetAsync(d_ws, 0, 340000, stream);
  k_gemm_scat<<<SCB + GMB, 256, 0, stream>>>(x, W1, h1, src, dst, cur, slots);
  k_gather1<<<NN / 4, 256, 0, stream>>>(slots, cur, b1, h1, a1);
  k_final4<<<NN / 4, 1024, 0, stream>>>(slots, cur, a1, W2, b2, out);
}

// Round 16
// 324.840 us; speedup vs baseline: 1.5402x; 1.5402x over previous
//
#include <hip/hip_runtime.h>
#include <math.h>

#define NN 5000
#define NE 160000
#define NF 16
#define KS 640      // k per split (8 splits: 7x640 + 520)
#define WTS 648     // LDS k-stride (bf16): 324 words, %32=4 -> 2-way alias = free
#define CAP 128     // per-node edge bucket capacity (max in-deg ~65 @ lambda=32)
#define SCB 625     // scatter-role blocks (625*256 = 160000 = NE exact)
#define GMB 632     // gemm-role blocks (79 x-tiles * 8 k-splits)

typedef __attribute__((ext_vector_type(8))) short bf16x8;  // 4 VGPRs
typedef __attribute__((ext_vector_type(4))) float f32x4;   // MFMA acc

// ws layout (bytes):
// [0,       20000)   cur   : per-node cursor -> in-degree after scatter (zeroed)
// [20000,   340000)  h1    : x@W1 (split-k atomics -> zeroed)
// [340000,  2900000) slots : bucketed edge sources, slots[d*CAP+pos]=src
// [2900000, 3220000) a1    : relu(agg1(h1)+b1)

__device__ __forceinline__ short f2bf(float f) {  // RNE f32->bf16
  union { float f; unsigned u; } v; v.f = f;
  unsigned r = v.u + 0x7FFFu + ((v.u >> 16) & 1u);
  return (short)(r >> 16);
}

// Merged kernel: blocks [0,SCB) bucket edges by dst; blocks [SCB, SCB+GMB)
// compute h1 = x @ W1 via mfma_f32_16x16x32_bf16 (fp32 acc), split-k x8.
__global__ __launch_bounds__(256) void k_gemm_scat(const float* __restrict__ x,
                                                   const float* __restrict__ w1,
                                                   float* __restrict__ h1,
                                                   const int* __restrict__ src,
                                                   const int* __restrict__ dst,
                                                   int* __restrict__ cur,
                                                   int* __restrict__ slots) {
  __shared__ short wt[NF * WTS];  // 20736 B (unused by scatter role)
  const int bid = blockIdx.x;
  const int tid = threadIdx.x;

  if (bid < SCB) {                // ---- scatter role ----
    const int e = bid * 256 + tid;
    if (e < NE) {
      const int d = dst[e];
      const int pos = atomicAdd(&cur[d], 1);
      if (pos < CAP) slots[d * CAP + pos] = src[e];
    }
    return;                       // uniform per block; no barrier crossed
  }

  // ---- gemm role ----
  const int gb = bid - SCB;       // 0..631
  const int bx = gb % 79;
  const int by = gb / 79;
  const int lane = tid & 63;
  const int wv = tid >> 6;
  const int kb = by * KS;
  const int klen = (NN - kb < KS) ? (NN - kb) : KS;   // 640 or 520
  const int nsteps = (klen + 31) >> 5;                // 20 or 17

  // Stage W1[kb..kb+KS) -> wt[n][kk] transposed bf16, zero-padded past NN.
  for (int kk = tid; kk < KS; kk += 256) {
    const int kg = kb + kk;
    if (kg < NN) {
      const float4* __restrict__ wr = (const float4*)(w1 + (size_t)kg * NF);
      const float4 a = wr[0], b = wr[1], c = wr[2], d = wr[3];
      wt[0 * WTS + kk] = f2bf(a.x);  wt[1 * WTS + kk] = f2bf(a.y);
      wt[2 * WTS + kk] = f2bf(a.z);  wt[3 * WTS + kk] = f2bf(a.w);
      wt[4 * WTS + kk] = f2bf(b.x);  wt[5 * WTS + kk] = f2bf(b.y);
      wt[6 * WTS + kk] = f2bf(b.z);  wt[7 * WTS + kk] = f2bf(b.w);
      wt[8 * WTS + kk] = f2bf(c.x);  wt[9 * WTS + kk] = f2bf(c.y);
      wt[10 * WTS + kk] = f2bf(c.z); wt[11 * WTS + kk] = f2bf(c.w);
      wt[12 * WTS + kk] = f2bf(d.x); wt[13 * WTS + kk] = f2bf(d.y);
      wt[14 * WTS + kk] = f2bf(d.z); wt[15 * WTS + kk] = f2bf(d.w);
    } else {
#pragma unroll
      for (int n = 0; n < NF; ++n) wt[n * WTS + kk] = 0;
    }
  }
  __syncthreads();

  const int tile = bx * 4 + wv;   // 0..315 (313 real)
  const int m0 = tile * 16;
  int arow = m0 + (lane & 15);
  if (arow > NN - 1) arow = NN - 1;       // clamp addr; write guarded below
  const float* __restrict__ xr = x + (size_t)arow * NN + kb;
  const int quad = lane >> 4;
  const short* __restrict__ bp = &wt[(lane & 15) * WTS + quad * 8];

  f32x4 acc = {0.f, 0.f, 0.f, 0.f};
  for (int s = 0; s < nsteps; ++s) {
    const int k0 = s * 32 + quad * 8;     // offset within split (8-aligned)
    bf16x8 a;
    if (kb + k0 < NN) {                   // whole 8-chunk valid (NN%8==0)
      const float4 xa = *(const float4*)(xr + k0);
      const float4 xb = *(const float4*)(xr + k0 + 4);
      a[0] = f2bf(xa.x); a[1] = f2bf(xa.y); a[2] = f2bf(xa.z); a[3] = f2bf(xa.w);
      a[4] = f2bf(xb.x); a[5] = f2bf(xb.y); a[6] = f2bf(xb.z); a[7] = f2bf(xb.w);
    } else {
#pragma unroll
      for (int j = 0; j < 8; ++j) a[j] = 0;
    }
    const bf16x8 b = *(const bf16x8*)(bp + s * 32);  // ds_read_b128
    acc = __builtin_amdgcn_mfma_f32_16x16x32_bf16(a, b, acc, 0, 0, 0);
  }

  const int col = lane & 15;
#pragma unroll
  for (int r = 0; r < 4; ++r) {
    const int orow = m0 + quad * 4 + r;
    if (orow < NN) atomicAdd(&h1[orow * NF + col], acc[r]);
  }
}

// Layer-1 aggregation (gather, no atomics), fused bias+ReLU:
//   a1[v][j] = relu(inv[v]*sum_s inv[s]*h1[s][j] + inv[v]^2*h1[v][j] + b1[j])
__global__ __launch_bounds__(256) void k_gather1(const int* __restrict__ slots,
                                                 const int* __restrict__ cnt,
                                                 const float* __restrict__ bias,
                                                 const float* __restrict__ hin,
                                                 float* __restrict__ outp) {
  const int tid = threadIdx.x;
  const int lane = tid & 63;
  const int wv = tid >> 6;
  const int v = blockIdx.x * 4 + wv;
  if (v >= NN) return;
  const int j = lane & 15;
  const int eg = lane >> 4;                 // edge subgroup 0..3
  int deg = cnt[v];
  if (deg > CAP) deg = CAP;
  const int* __restrict__ sl = slots + v * CAP;

  float acc = 0.f;
  int base = 0;
  for (; base + 8 <= deg; base += 8) {      // 2 independent chains per iter
    const int s0 = sl[base + eg];
    const int s1 = sl[base + 4 + eg];
    const float iv0 = rsqrtf((float)cnt[s0] + 1.0f);
    const float iv1 = rsqrtf((float)cnt[s1] + 1.0f);
    acc += iv0 * hin[s0 * NF + j];
    acc += iv1 * hin[s1 * NF + j];
  }
  for (; base < deg; base += 4) {
    const int idx = base + eg;
    if (idx < deg) {
      const int s = sl[idx];
      acc += rsqrtf((float)cnt[s] + 1.0f) * hin[s * NF + j];
    }
  }
  acc += __shfl_xor(acc, 16);
  acc += __shfl_xor(acc, 32);

  if (lane < 16) {
    const float ivv = rsqrtf((float)deg + 1.0f);
    float r = ivv * acc + ivv * ivv * hin[v * NF + j];
    outp[v * NF + j] = fmaxf(r + bias[j], 0.f);
  }
}

// One column-chunk of z = g @ W2 + b2 (4 rows x 4 cols, all static indices).
__device__ __forceinline__ void zchunk(const float (&g)[4][NF],
                                       const float* __restrict__ w2,
                                       const float* __restrict__ b2,
                                       int c, float (&z)[4][4]) {
  const float4 bb = *(const float4*)(b2 + c);
#pragma unroll
  for (int r = 0; r < 4; ++r) {
    z[r][0] = bb.x; z[r][1] = bb.y; z[r][2] = bb.z; z[r][3] = bb.w;
  }
#pragma unroll
  for (int k = 0; k < NF; ++k) {
    const float4 w = *(const float4*)(w2 + (size_t)k * NN + c);
#pragma unroll
    for (int r = 0; r < 4; ++r) {
      z[r][0] = fmaf(g[r][k], w.x, z[r][0]);
      z[r][1] = fmaf(g[r][k], w.y, z[r][1]);
      z[r][2] = fmaf(g[r][k], w.z, z[r][2]);
      z[r][3] = fmaf(g[r][k], w.w, z[r][3]);
    }
  }
}

// Fused layer-2 aggregation + final GEMM + log_softmax. 4 rows per block,
// 512 threads (8 waves = 2/SIMD -> VGPR cap 256: room for g[64]+z[48], NO
// spill -- round 10's 1024-thread version spilled at the 64-VGPR cap).
// z entirely in registers; w2/b2/out via float4; no zs LDS.
__global__ __launch_bounds__(512) void k_final5(const int* __restrict__ slots,
                                                const int* __restrict__ cnt,
                                                const float* __restrict__ a1,
                                                const float* __restrict__ w2,
                                                const float* __restrict__ b2,
                                                float* __restrict__ out) {
  __shared__ float pp[8][NF];       // per-wave gather partials
  __shared__ float gsh[4 * NF];
  __shared__ float red[8 * 4];
  __shared__ float rowmax[4];
  __shared__ float rowoff[4];
  const int tid = threadIdx.x;
  const int lane = tid & 63;
  const int wv = tid >> 6;          // 0..7
  const int row0 = blockIdx.x * 4;

  // ---- phase 1: gather g2 rows (2 waves/node, 8 edge-subgroups each) ----
  {
    const int r = wv >> 1;                          // node 0..3
    const int v = row0 + r;
    const int j = lane & 15;
    const int sg = ((wv & 1) << 2) | (lane >> 4);   // 0..7, stride 8
    int deg = cnt[v];
    if (deg > CAP) deg = CAP;
    const int* __restrict__ sl = slots + v * CAP;
    float acc = 0.f;
    for (int idx = sg; idx < deg; idx += 8) {
      const int s = sl[idx];
      acc += rsqrtf((float)cnt[s] + 1.0f) * a1[s * NF + j];
    }
    acc += __shfl_xor(acc, 16);
    acc += __shfl_xor(acc, 32);
    if (lane < 16) pp[wv][j] = acc;
  }
  __syncthreads();
  if (tid < 64) {
    const int r = tid >> 4, j = tid & 15;
    const int v = row0 + r;
    int deg = cnt[v];
    if (deg > CAP) deg = CAP;
    const float ivv = rsqrtf((float)deg + 1.0f);
    const float acc = pp[r * 2 + 0][j] + pp[r * 2 + 1][j];
    gsh[r * NF + j] = ivv * acc + ivv * ivv * a1[v * NF + j];
  }
  __syncthreads();

  // ---- phase 2: z = g2 @ W2 + b2, all-register z, float4 memory ----
  float g[4][NF];
#pragma unroll
  for (int r = 0; r < 4; ++r)
#pragma unroll
    for (int k = 0; k < NF; ++k) g[r][k] = gsh[r * NF + k];

  const int c0 = tid * 4;               // [0, 2048)
  const int c1 = 2048 + tid * 4;        // [2048, 4096)
  const int c2 = 4096 + tid * 4;        // [4096, 5000) for tid<226 (226*4=904)
  const bool act2 = (tid < 226);

  float zA[4][4], zB[4][4], zC[4][4];
  zchunk(g, w2, b2, c0, zA);
  zchunk(g, w2, b2, c1, zB);
  if (act2) zchunk(g, w2, b2, c2, zC);

  // block-wide row max
  float mx[4];
#pragma unroll
  for (int r = 0; r < 4; ++r) {
    float m = fmaxf(fmaxf(zA[r][0], zA[r][1]), fmaxf(zA[r][2], zA[r][3]));
    m = fmaxf(m, fmaxf(fmaxf(zB[r][0], zB[r][1]), fmaxf(zB[r][2], zB[r][3])));
    if (act2)
      m = fmaxf(m, fmaxf(fmaxf(zC[r][0], zC[r][1]), fmaxf(zC[r][2], zC[r][3])));
    for (int off = 32; off; off >>= 1) m = fmaxf(m, __shfl_xor(m, off));
    mx[r] = m;
  }
  if (lane == 0) {
#pragma unroll
    for (int r = 0; r < 4; ++r) red[wv * 4 + r] = mx[r];
  }
  __syncthreads();
  if (tid < 4) {
    float m = red[tid];
#pragma unroll
    for (int w = 1; w < 8; ++w) m = fmaxf(m, red[w * 4 + tid]);
    rowmax[tid] = m;
  }
  __syncthreads();

  // block-wide row sum of exp(z - rowmax), z from registers
  {
    const float rms[4] = {rowmax[0], rowmax[1], rowmax[2], rowmax[3]};
    float sm[4];
#pragma unroll
    for (int r = 0; r < 4; ++r) {
      float s = __expf(zA[r][0] - rms[r]) + __expf(zA[r][1] - rms[r]) +
                __expf(zA[r][2] - rms[r]) + __expf(zA[r][3] - rms[r]);
      s += __expf(zB[r][0] - rms[r]) + __expf(zB[r][1] - rms[r]) +
           __expf(zB[r][2] - rms[r]) + __expf(zB[r][3] - rms[r]);
      if (act2)
        s += __expf(zC[r][0] - rms[r]) + __expf(zC[r][1] - rms[r]) +
             __expf(zC[r][2] - rms[r]) + __expf(zC[r][3] - rms[r]);
      for (int off = 32; off; off >>= 1) s += __shfl_xor(s, off);
      sm[r] = s;
    }
    if (lane == 0) {
#pragma unroll
      for (int r = 0; r < 4; ++r) red[wv * 4 + r] = sm[r];
    }
  }
  __syncthreads();
  if (tid < 4) {
    float s = red[tid];
#pragma unroll
    for (int w = 1; w < 8; ++w) s += red[w * 4 + tid];
    rowoff[tid] = rowmax[tid] + logf(s);
  }
  __syncthreads();

  // write out = z - rowoff, float4 stores from registers
  {
    const float o[4] = {rowoff[0], rowoff[1], rowoff[2], rowoff[3]};
#pragma unroll
    for (int r = 0; r < 4; ++r) {
      float* __restrict__ orow = out + (size_t)(row0 + r) * NN;
      float4 v;
      v.x = zA[r][0] - o[r]; v.y = zA[r][1] - o[r];
      v.z = zA[r][2] - o[r]; v.w = zA[r][3] - o[r];
      *(float4*)(orow + c0) = v;
      v.x = zB[r][0] - o[r]; v.y = zB[r][1] - o[r];
      v.z = zB[r][2] - o[r]; v.w = zB[r][3] - o[r];
      *(float4*)(orow + c1) = v;
      if (act2) {
        v.x = zC[r][0] - o[r]; v.y = zC[r][1] - o[r];
        v.z = zC[r][2] - o[r]; v.w = zC[r][3] - o[r];
        *(float4*)(orow + c2) = v;
      }
    }
  }
}

extern "C" void kernel_launch(void* const* d_in, const int* in_sizes, int n_in,
                              void* d_out, int out_size, void* d_ws, size_t ws_size,
                              hipStream_t stream) {
  const float* x  = (const float*)d_in[0];
  const int*   src = (const int*)d_in[1];
  const int*   dst = (const int*)d_in[2];
  const float* W1 = (const float*)d_in[3];
  const float* b1 = (const float*)d_in[4];
  const float* W2 = (const float*)d_in[5];
  const float* b2 = (const float*)d_in[6];
  float* out = (float*)d_out;

  char* ws = (char*)d_ws;
  int*   cur   = (int*)(ws);                // [0, 20000)
  float* h1    = (float*)(ws + 20000);      // [20000, 340000)
  int*   slots = (int*)(ws + 340000);       // [340000, 2900000)
  float* a1    = (float*)(ws + 2900000);    // [2900000, 3220000)

  // zero cur + h1 (scatter cursors; split-k atomics accumulate into h1)
  hipMemsetAsync(d_ws, 0, 340000, stream);
  k_gemm_scat<<<SCB + GMB, 256, 0, stream>>>(x, W1, h1, src, dst, cur, slots);
  k_gather1<<<NN / 4, 256, 0, stream>>>(slots, cur, b1, h1, a1);
  k_final5<<<NN / 4, 512, 0, stream>>>(slots, cur, a1, W2, b2, out);
}

// Round 17
// 324.373 us; speedup vs baseline: 1.5424x; 1.0014x over previous
//
#include <hip/hip_runtime.h>
#include <math.h>

#define NN 5000
#define NE 160000
#define NF 16
#define KS 640      // k per split (8 splits: 7x640 + 520)
#define WTS 648     // LDS k-stride (bf16): 324 words, %32=4 -> 2-way alias = free
#define CAP 128     // per-node edge bucket capacity (max in-deg ~65 @ lambda=32)
#define SCB 625     // scatter-role blocks (625*256 = 160000 = NE exact)
#define GMB 632     // gemm-role blocks (79 x-tiles * 8 k-splits)

typedef __attribute__((ext_vector_type(8))) short bf16x8;  // 4 VGPRs
typedef __attribute__((ext_vector_type(4))) float f32x4;   // MFMA acc

// ws layout (bytes):
// [0,       20000)   cur   : per-node cursor -> in-degree after scatter (zeroed)
// [20000,   340000)  h1    : x@W1 (split-k atomics -> zeroed)
// [340000,  2900000) slots : bucketed edge sources, slots[d*CAP+pos]=src
// [2900000, 3220000) a1    : relu(agg1(h1)+b1)

__device__ __forceinline__ short f2bf(float f) {  // RNE f32->bf16
  union { float f; unsigned u; } v; v.f = f;
  unsigned r = v.u + 0x7FFFu + ((v.u >> 16) & 1u);
  return (short)(r >> 16);
}

// Merged kernel: blocks [0,SCB) bucket edges by dst; blocks [SCB, SCB+GMB)
// compute h1 = x @ W1 via mfma_f32_16x16x32_bf16 (fp32 acc), split-k x8.
__global__ __launch_bounds__(256) void k_gemm_scat(const float* __restrict__ x,
                                                   const float* __restrict__ w1,
                                                   float* __restrict__ h1,
                                                   const int* __restrict__ src,
                                                   const int* __restrict__ dst,
                                                   int* __restrict__ cur,
                                                   int* __restrict__ slots) {
  __shared__ short wt[NF * WTS];  // 20736 B (unused by scatter role)
  const int bid = blockIdx.x;
  const int tid = threadIdx.x;

  if (bid < SCB) {                // ---- scatter role ----
    const int e = bid * 256 + tid;
    if (e < NE) {
      const int d = dst[e];
      const int pos = atomicAdd(&cur[d], 1);
      if (pos < CAP) slots[d * CAP + pos] = src[e];
    }
    return;                       // uniform per block; no barrier crossed
  }

  // ---- gemm role ----
  const int gb = bid - SCB;       // 0..631
  const int bx = gb % 79;
  const int by = gb / 79;
  const int lane = tid & 63;
  const int wv = tid >> 6;
  const int kb = by * KS;
  const int klen = (NN - kb < KS) ? (NN - kb) : KS;   // 640 or 520
  const int nsteps = (klen + 31) >> 5;                // 20 or 17

  // Stage W1[kb..kb+KS) -> wt[n][kk] transposed bf16, zero-padded past NN.
  for (int kk = tid; kk < KS; kk += 256) {
    const int kg = kb + kk;
    if (kg < NN) {
      const float4* __restrict__ wr = (const float4*)(w1 + (size_t)kg * NF);
      const float4 a = wr[0], b = wr[1], c = wr[2], d = wr[3];
      wt[0 * WTS + kk] = f2bf(a.x);  wt[1 * WTS + kk] = f2bf(a.y);
      wt[2 * WTS + kk] = f2bf(a.z);  wt[3 * WTS + kk] = f2bf(a.w);
      wt[4 * WTS + kk] = f2bf(b.x);  wt[5 * WTS + kk] = f2bf(b.y);
      wt[6 * WTS + kk] = f2bf(b.z);  wt[7 * WTS + kk] = f2bf(b.w);
      wt[8 * WTS + kk] = f2bf(c.x);  wt[9 * WTS + kk] = f2bf(c.y);
      wt[10 * WTS + kk] = f2bf(c.z); wt[11 * WTS + kk] = f2bf(c.w);
      wt[12 * WTS + kk] = f2bf(d.x); wt[13 * WTS + kk] = f2bf(d.y);
      wt[14 * WTS + kk] = f2bf(d.z); wt[15 * WTS + kk] = f2bf(d.w);
    } else {
#pragma unroll
      for (int n = 0; n < NF; ++n) wt[n * WTS + kk] = 0;
    }
  }
  __syncthreads();

  const int tile = bx * 4 + wv;   // 0..315 (313 real)
  const int m0 = tile * 16;
  int arow = m0 + (lane & 15);
  if (arow > NN - 1) arow = NN - 1;       // clamp addr; write guarded below
  const float* __restrict__ xr = x + (size_t)arow * NN + kb;
  const int quad = lane >> 4;
  const short* __restrict__ bp = &wt[(lane & 15) * WTS + quad * 8];

  f32x4 acc = {0.f, 0.f, 0.f, 0.f};
  for (int s = 0; s < nsteps; ++s) {
    const int k0 = s * 32 + quad * 8;     // offset within split (8-aligned)
    bf16x8 a;
    if (kb + k0 < NN) {                   // whole 8-chunk valid (NN%8==0)
      const float4 xa = *(const float4*)(xr + k0);
      const float4 xb = *(const float4*)(xr + k0 + 4);
      a[0] = f2bf(xa.x); a[1] = f2bf(xa.y); a[2] = f2bf(xa.z); a[3] = f2bf(xa.w);
      a[4] = f2bf(xb.x); a[5] = f2bf(xb.y); a[6] = f2bf(xb.z); a[7] = f2bf(xb.w);
    } else {
#pragma unroll
      for (int j = 0; j < 8; ++j) a[j] = 0;
    }
    const bf16x8 b = *(const bf16x8*)(bp + s * 32);  // ds_read_b128
    acc = __builtin_amdgcn_mfma_f32_16x16x32_bf16(a, b, acc, 0, 0, 0);
  }

  const int col = lane & 15;
#pragma unroll
  for (int r = 0; r < 4; ++r) {
    const int orow = m0 + quad * 4 + r;
    if (orow < NN) atomicAdd(&h1[orow * NF + col], acc[r]);
  }
}

// Layer-1 aggregation (gather, no atomics), fused bias+ReLU:
//   a1[v][j] = relu(inv[v]*sum_s inv[s]*h1[s][j] + inv[v]^2*h1[v][j] + b1[j])
__global__ __launch_bounds__(256) void k_gather1(const int* __restrict__ slots,
                                                 const int* __restrict__ cnt,
                                                 const float* __restrict__ bias,
                                                 const float* __restrict__ hin,
                                                 float* __restrict__ outp) {
  const int tid = threadIdx.x;
  const int lane = tid & 63;
  const int wv = tid >> 6;
  const int v = blockIdx.x * 4 + wv;
  if (v >= NN) return;
  const int j = lane & 15;
  const int eg = lane >> 4;                 // edge subgroup 0..3
  int deg = cnt[v];
  if (deg > CAP) deg = CAP;
  const int* __restrict__ sl = slots + v * CAP;

  float acc = 0.f;
  int base = 0;
  for (; base + 8 <= deg; base += 8) {      // 2 independent chains per iter
    const int s0 = sl[base + eg];
    const int s1 = sl[base + 4 + eg];
    const float iv0 = rsqrtf((float)cnt[s0] + 1.0f);
    const float iv1 = rsqrtf((float)cnt[s1] + 1.0f);
    acc += iv0 * hin[s0 * NF + j];
    acc += iv1 * hin[s1 * NF + j];
  }
  for (; base < deg; base += 4) {
    const int idx = base + eg;
    if (idx < deg) {
      const int s = sl[idx];
      acc += rsqrtf((float)cnt[s] + 1.0f) * hin[s * NF + j];
    }
  }
  acc += __shfl_xor(acc, 16);
  acc += __shfl_xor(acc, 32);

  if (lane < 16) {
    const float ivv = rsqrtf((float)deg + 1.0f);
    float r = ivv * acc + ivv * ivv * hin[v * NF + j];
    outp[v * NF + j] = fmaxf(r + bias[j], 0.f);
  }
}

// One column-chunk of z = g @ W2 + b2 (4 rows x 4 cols, all static indices).
__device__ __forceinline__ void zchunk(const float (&g)[4][NF],
                                       const float* __restrict__ w2,
                                       const float* __restrict__ b2,
                                       int c, float (&z)[4][4]) {
  const float4 bb = *(const float4*)(b2 + c);
#pragma unroll
  for (int r = 0; r < 4; ++r) {
    z[r][0] = bb.x; z[r][1] = bb.y; z[r][2] = bb.z; z[r][3] = bb.w;
  }
#pragma unroll
  for (int k = 0; k < NF; ++k) {
    const float4 w = *(const float4*)(w2 + (size_t)k * NN + c);
#pragma unroll
    for (int r = 0; r < 4; ++r) {
      z[r][0] = fmaf(g[r][k], w.x, z[r][0]);
      z[r][1] = fmaf(g[r][k], w.y, z[r][1]);
      z[r][2] = fmaf(g[r][k], w.z, z[r][2]);
      z[r][3] = fmaf(g[r][k], w.w, z[r][3]);
    }
  }
}

// Fused layer-2 aggregation + final GEMM + log_softmax. 4 rows per block,
// 512 threads. __launch_bounds__(512, 2): 2 waves/EU min -> 1 block/CU ->
// VGPR cap 256 (round 16 showed default targets 2 blk/CU, caps at 128,
// and spills ~20 VGPR -> 300 MB scratch traffic, 134 us). ~150 live VGPRs
// now fit. z entirely in registers; w2/b2/out via float4; no zs LDS.
__global__ __launch_bounds__(512, 2) void k_final5(const int* __restrict__ slots,
                                                   const int* __restrict__ cnt,
                                                   const float* __restrict__ a1,
                                                   const float* __restrict__ w2,
                                                   const float* __restrict__ b2,
                                                   float* __restrict__ out) {
  __shared__ float pp[8][NF];       // per-wave gather partials
  __shared__ float gsh[4 * NF];
  __shared__ float red[8 * 4];
  __shared__ float rowmax[4];
  __shared__ float rowoff[4];
  const int tid = threadIdx.x;
  const int lane = tid & 63;
  const int wv = tid >> 6;          // 0..7
  const int row0 = blockIdx.x * 4;

  // ---- phase 1: gather g2 rows (2 waves/node, 8 edge-subgroups each) ----
  {
    const int r = wv >> 1;                          // node 0..3
    const int v = row0 + r;
    const int j = lane & 15;
    const int sg = ((wv & 1) << 2) | (lane >> 4);   // 0..7, stride 8
    int deg = cnt[v];
    if (deg > CAP) deg = CAP;
    const int* __restrict__ sl = slots + v * CAP;
    float acc = 0.f;
    for (int idx = sg; idx < deg; idx += 8) {
      const int s = sl[idx];
      acc += rsqrtf((float)cnt[s] + 1.0f) * a1[s * NF + j];
    }
    acc += __shfl_xor(acc, 16);
    acc += __shfl_xor(acc, 32);
    if (lane < 16) pp[wv][j] = acc;
  }
  __syncthreads();
  if (tid < 64) {
    const int r = tid >> 4, j = tid & 15;
    const int v = row0 + r;
    int deg = cnt[v];
    if (deg > CAP) deg = CAP;
    const float ivv = rsqrtf((float)deg + 1.0f);
    const float acc = pp[r * 2 + 0][j] + pp[r * 2 + 1][j];
    gsh[r * NF + j] = ivv * acc + ivv * ivv * a1[v * NF + j];
  }
  __syncthreads();

  // ---- phase 2: z = g2 @ W2 + b2, all-register z, float4 memory ----
  float g[4][NF];
#pragma unroll
  for (int r = 0; r < 4; ++r)
#pragma unroll
    for (int k = 0; k < NF; ++k) g[r][k] = gsh[r * NF + k];

  const int c0 = tid * 4;               // [0, 2048)
  const int c1 = 2048 + tid * 4;        // [2048, 4096)
  const int c2 = 4096 + tid * 4;        // [4096, 5000) for tid<226 (226*4=904)
  const bool act2 = (tid < 226);

  float zA[4][4], zB[4][4], zC[4][4];
  zchunk(g, w2, b2, c0, zA);
  zchunk(g, w2, b2, c1, zB);
  if (act2) zchunk(g, w2, b2, c2, zC);

  // block-wide row max
  float mx[4];
#pragma unroll
  for (int r = 0; r < 4; ++r) {
    float m = fmaxf(fmaxf(zA[r][0], zA[r][1]), fmaxf(zA[r][2], zA[r][3]));
    m = fmaxf(m, fmaxf(fmaxf(zB[r][0], zB[r][1]), fmaxf(zB[r][2], zB[r][3])));
    if (act2)
      m = fmaxf(m, fmaxf(fmaxf(zC[r][0], zC[r][1]), fmaxf(zC[r][2], zC[r][3])));
    for (int off = 32; off; off >>= 1) m = fmaxf(m, __shfl_xor(m, off));
    mx[r] = m;
  }
  if (lane == 0) {
#pragma unroll
    for (int r = 0; r < 4; ++r) red[wv * 4 + r] = mx[r];
  }
  __syncthreads();
  if (tid < 4) {
    float m = red[tid];
#pragma unroll
    for (int w = 1; w < 8; ++w) m = fmaxf(m, red[w * 4 + tid]);
    rowmax[tid] = m;
  }
  __syncthreads();

  // block-wide row sum of exp(z - rowmax), z from registers
  {
    const float rms[4] = {rowmax[0], rowmax[1], rowmax[2], rowmax[3]};
    float sm[4];
#pragma unroll
    for (int r = 0; r < 4; ++r) {
      float s = __expf(zA[r][0] - rms[r]) + __expf(zA[r][1] - rms[r]) +
                __expf(zA[r][2] - rms[r]) + __expf(zA[r][3] - rms[r]);
      s += __expf(zB[r][0] - rms[r]) + __expf(zB[r][1] - rms[r]) +
           __expf(zB[r][2] - rms[r]) + __expf(zB[r][3] - rms[r]);
      if (act2)
        s += __expf(zC[r][0] - rms[r]) + __expf(zC[r][1] - rms[r]) +
             __expf(zC[r][2] - rms[r]) + __expf(zC[r][3] - rms[r]);
      for (int off = 32; off; off >>= 1) s += __shfl_xor(s, off);
      sm[r] = s;
    }
    if (lane == 0) {
#pragma unroll
      for (int r = 0; r < 4; ++r) red[wv * 4 + r] = sm[r];
    }
  }
  __syncthreads();
  if (tid < 4) {
    float s = red[tid];
#pragma unroll
    for (int w = 1; w < 8; ++w) s += red[w * 4 + tid];
    rowoff[tid] = rowmax[tid] + logf(s);
  }
  __syncthreads();

  // write out = z - rowoff, float4 stores from registers
  {
    const float o[4] = {rowoff[0], rowoff[1], rowoff[2], rowoff[3]};
#pragma unroll
    for (int r = 0; r < 4; ++r) {
      float* __restrict__ orow = out + (size_t)(row0 + r) * NN;
      float4 v;
      v.x = zA[r][0] - o[r]; v.y = zA[r][1] - o[r];
      v.z = zA[r][2] - o[r]; v.w = zA[r][3] - o[r];
      *(float4*)(orow + c0) = v;
      v.x = zB[r][0] - o[r]; v.y = zB[r][1] - o[r];
      v.z = zB[r][2] - o[r]; v.w = zB[r][3] - o[r];
      *(float4*)(orow + c1) = v;
      if (act2) {
        v.x = zC[r][0] - o[r]; v.y = zC[r][1] - o[r];
        v.z = zC[r][2] - o[r]; v.w = zC[r][3] - o[r];
        *(float4*)(orow + c2) = v;
      }
    }
  }
}

extern "C" void kernel_launch(void* const* d_in, const int* in_sizes, int n_in,
                              void* d_out, int out_size, void* d_ws, size_t ws_size,
                              hipStream_t stream) {
  const float* x  = (const float*)d_in[0];
  const int*   src = (const int*)d_in[1];
  const int*   dst = (const int*)d_in[2];
  const float* W1 = (const float*)d_in[3];
  const float* b1 = (const float*)d_in[4];
  const float* W2 = (const float*)d_in[5];
  const float* b2 = (const float*)d_in[6];
  float* out = (float*)d_out;

  char* ws = (char*)d_ws;
  int*   cur   = (int*)(ws);                // [0, 20000)
  float* h1    = (float*)(ws + 20000);      // [20000, 340000)
  int*   slots = (int*)(ws + 340000);       // [340000, 2900000)
  float* a1    = (float*)(ws + 2900000);    // [2900000, 3220000)

  // zero cur + h1 (scatter cursors; split-k atomics accumulate into h1)
  hipMemsetAsync(d_ws, 0, 340000, stream);
  k_gemm_scat<<<SCB + GMB, 256, 0, stream>>>(x, W1, h1, src, dst, cur, slots);
  k_gather1<<<NN / 4, 256, 0, stream>>>(slots, cur, b1, h1, a1);
  k_final5<<<NN / 4, 512, 0, stream>>>(slots, cur, a1, W2, b2, out);
}